// Round 14
// baseline (191.521 us; speedup 1.0000x reference)
//
#include <hip/hip_runtime.h>
#include <hip/hip_bf16.h>
#include <math.h>

#define Nn 8192
#define Mm 8192
#define DIM 128
#define EPS 0.001
#define RBAND 32     // 32 ck col-chunks -> fully fr-reduced row bands
#define CBAND 64     // 64 bi row-blocks -> fully (wv,fg)-reduced col bands

typedef __attribute__((ext_vector_type(8))) short bf16x8;
typedef __attribute__((ext_vector_type(4))) float f32x4;
typedef __attribute__((ext_vector_type(4))) float f4;
typedef __attribute__((ext_vector_type(4))) unsigned int u32x4;

__device__ __forceinline__ unsigned int pack2bf(float a, float b) {
  __hip_bfloat16 ha = __float2bfloat16(a), hb = __float2bfloat16(b);
  return (unsigned int)*(unsigned short*)&ha | ((unsigned int)*(unsigned short*)&hb << 16);
}

// keep a value alive without cost (rule #17: ablation-via-skip DCEs upstream ops)
__device__ __forceinline__ void sink_f4(f32x4 v) {
  asm volatile("" :: "v"(v[0]), "v"(v[1]), "v"(v[2]), "v"(v[3]));
}
__device__ __forceinline__ void sink_bf(bf16x8 v) {
  f32x4 f = __builtin_bit_cast(f32x4, v);
  asm volatile("" :: "v"(f[0]), "v"(f[1]), "v"(f[2]), "v"(f[3]));
}

// ---- prep: FRAGMENT-MAJOR bf16 for both X and Y + squared norms (proven R5-R13). ----
__global__ __launch_bounds__(256) void prep_all(const float* __restrict__ X,
    const float* __restrict__ Y, unsigned short* __restrict__ Xf,
    unsigned short* __restrict__ Yf, float* __restrict__ X2, float* __restrict__ Y2) {
  int bid = blockIdx.x;                               // 1024 blocks: 512 X + 512 Y
  const float* src = (bid < 512) ? X : Y;
  unsigned short* dst = (bid < 512) ? Xf : Yf;
  float* dn = (bid < 512) ? X2 : Y2;
  int gid = (bid & 511) * 256 + threadIdx.x;          // 131072 = 8192 rows x 16 g
  int row = gid >> 4, g = gid & 15;
  f4 p0 = *(const f4*)(src + (size_t)row * DIM + g * 8);
  f4 p1 = *(const f4*)(src + (size_t)row * DIM + g * 8 + 4);
  u32x4 packed;
  packed[0] = pack2bf(p0[0], p0[1]);
  packed[1] = pack2bf(p0[2], p0[3]);
  packed[2] = pack2bf(p1[0], p1[1]);
  packed[3] = pack2bf(p1[2], p1[3]);
  int kk = g >> 2, fg = g & 3, t = row >> 4, fr = row & 15;
  *(u32x4*)(dst + (size_t)t * 2048 + kk * 512 + (fg * 16 + fr) * 8) = packed;
  float s = p0[0]*p0[0] + p0[1]*p0[1] + p0[2]*p0[2] + p0[3]*p0[3]
          + p1[0]*p1[0] + p1[1]*p1[1] + p1[2]*p1[2] + p1[3]*p1[3];
  s += __shfl_xor(s, 1, 64); s += __shfl_xor(s, 2, 64);
  s += __shfl_xor(s, 4, 64); s += __shfl_xor(s, 8, 64);
  if (g == 0) dn[row] = s;
}

// issue one 1KB wave-DMA: global (per-lane addr) -> LDS (wave-uniform base + lane*16)
#define GLOAD_LDS16(gsrc, ldst) \
  __builtin_amdgcn_global_load_lds( \
      (const __attribute__((address_space(1))) unsigned int*)(gsrc), \
      (__attribute__((address_space(3))) unsigned int*)(ldst), 16, 0, 0)

// ---- fused stripe-sweep v5 (byte-identical hot structure to R13) ----
__global__ __launch_bounds__(256) void fused_sweep(const unsigned short* __restrict__ xf,
    const unsigned short* __restrict__ yf, const float* __restrict__ x2,
    const float* __restrict__ y2, float* __restrict__ Rpart, float* __restrict__ Cpart,
    float* __restrict__ wmaxp) {
  int bid = blockIdx.x;            // 2048 = 64 row-blocks x 32 chunks
  int bi = bid >> 5;               // row-block 0..63 (128 rows)
  int ck = bid & 31;               // col-chunk 0..31 (256 cols)
  int wv = threadIdx.x >> 6, lane = threadIdx.x & 63;
  int fr = lane & 15, fg = lane >> 4;
  int r0 = bi * 128 + wv * 32;

  __shared__ __attribute__((aligned(16))) unsigned short bld[2][4096];
  __shared__ float csum_s[16 * 256];
  __shared__ float rsum_s[4 * 512];
  __shared__ float y2s[256];
  __shared__ float smax[4];

  y2s[threadIdx.x] = y2[ck * 256 + threadIdx.x];

  bf16x8 a0[4], a1[4];
  #pragma unroll
  for (int kk = 0; kk < 4; ++kk) {
    a0[kk] = *(const bf16x8*)(xf + (size_t)(bi * 8 + wv * 2) * 2048 + kk * 512 + lane * 8);
    a1[kk] = *(const bf16x8*)(xf + (size_t)(bi * 8 + wv * 2 + 1) * 2048 + kk * 512 + lane * 8);
  }
  f4 xi0 = *(const f4*)(x2 + r0 + fg * 4);
  f4 xi1 = *(const f4*)(x2 + r0 + 16 + fg * 4);

  #define STAGE(buf, pj) do { \
    const unsigned short* _g = yf + (size_t)(ck * 16 + (pj) * 2) * 2048; \
    _Pragma("unroll") \
    for (int q = 0; q < 2; ++q) { \
      int s_ = q * 4 + wv; \
      GLOAD_LDS16(_g + s_ * 512 + lane * 8, &bld[buf][s_ * 512]); \
    } \
  } while (0)

  STAGE(0, 0);
  __syncthreads();

  float rs0[4] = {0.f,0.f,0.f,0.f};
  float rs1[4] = {0.f,0.f,0.f,0.f};
  float dm = 0.f;
  int cq = (wv * 4 + fg) * 256;
  int cur = 0;

  for (int j = 0; j < 8; ++j) {
    if (j < 7) {
      STAGE(cur ^ 1, j + 1);
      asm volatile("s_waitcnt vmcnt(2)" ::: "memory");
    } else {
      asm volatile("s_waitcnt vmcnt(0)" ::: "memory");
    }
    __builtin_amdgcn_s_barrier();

    #pragma unroll
    for (int n = 0; n < 2; ++n) {
      float y2n = y2s[j * 32 + n * 16 + fr];
      f32x4 acc0 = (f32x4){0.f,0.f,0.f,0.f};
      f32x4 acc1 = (f32x4){0.f,0.f,0.f,0.f};
      #pragma unroll
      for (int kk = 0; kk < 4; ++kk) {
        bf16x8 b = *(const bf16x8*)(&bld[cur][n * 2048 + kk * 512 + lane * 8]);
        acc0 = __builtin_amdgcn_mfma_f32_16x16x32_bf16(a0[kk], b, acc0, 0, 0, 0);
        acc1 = __builtin_amdgcn_mfma_f32_16x16x32_bf16(a1[kk], b, acc1, 0, 0, 0);
      }
      float cs = 0.f;
      #pragma unroll
      for (int r = 0; r < 4; ++r) {
        float d20 = xi0[r] + y2n - 2.0f * acc0[r];
        float d21 = xi1[r] + y2n - 2.0f * acc1[r];
        dm = fmaxf(dm, fmaxf(d20, d21));
        float w0 = __builtin_amdgcn_sqrtf(fmaxf(d20, 0.f));
        float w1 = __builtin_amdgcn_sqrtf(fmaxf(d21, 0.f));
        rs0[r] += w0; rs1[r] += w1;
        cs += w0 + w1;
      }
      csum_s[cq + j * 32 + n * 16 + fr] = cs;
    }
    __builtin_amdgcn_s_barrier();
    cur ^= 1;
  }

  #pragma unroll
  for (int r = 0; r < 4; ++r) {
    rsum_s[wv * 512 + fr * 32 + fg * 4 + r] = rs0[r];
    rsum_s[wv * 512 + fr * 32 + 16 + fg * 4 + r] = rs1[r];
  }
  float wm = __builtin_amdgcn_sqrtf(fmaxf(dm, 0.f));
  #pragma unroll
  for (int mask = 1; mask < 64; mask <<= 1) wm = fmaxf(wm, __shfl_xor(wm, mask, 64));
  if (lane == 0) smax[wv] = wm;
  __syncthreads();

  {
    int tid = threadIdx.x;
    float s = 0.f;
    #pragma unroll
    for (int q = 0; q < 16; ++q) s += csum_s[q * 256 + tid];
    Cpart[(size_t)bi * Mm + ck * 256 + tid] = s;
    if (tid < 128) {
      int w = tid >> 5, lr = tid & 31;
      float t2 = 0.f;
      #pragma unroll
      for (int f = 0; f < 16; ++f) t2 += rsum_s[w * 512 + f * 32 + lr];
      Rpart[(size_t)ck * Nn + bi * 128 + tid] = t2;
    }
    if (tid == 0)
      wmaxp[bid] = fmaxf(fmaxf(smax[0], smax[1]), fmaxf(smax[2], smax[3]));
  }
  #undef STAGE
}

// ---- DIAGNOSTIC ablation kernels (R14 only). Same geometry/LDS/occupancy as
// fused_sweep; j-loop repeated REP times for top-5 visibility over the harness
// fill kernels. MODE 0: stage+vmcnt+barrier skeleton. MODE 1: + ds_read + MFMA
// (acc kept live via asm sinks). MODE 2: full body. Writes only diag scratch. ----
template<int MODE, int REP>
__global__ __launch_bounds__(256) void fused_diag(const unsigned short* __restrict__ xf,
    const unsigned short* __restrict__ yf, const float* __restrict__ x2,
    const float* __restrict__ y2, float* __restrict__ diag) {
  int bid = blockIdx.x;
  int bi = bid >> 5, ck = bid & 31;
  int wv = threadIdx.x >> 6, lane = threadIdx.x & 63;
  int fr = lane & 15, fg = lane >> 4;
  int r0 = bi * 128 + wv * 32;

  __shared__ __attribute__((aligned(16))) unsigned short bld[2][4096];
  __shared__ float csum_s[16 * 256];
  __shared__ float rsum_s[4 * 512];
  __shared__ float y2s[256];
  __shared__ float smax[4];

  // force identical LDS footprint in all modes (occupancy parity with fused_sweep)
  { volatile float* t1 = csum_s; t1[threadIdx.x] = 0.f;
    volatile float* t2 = rsum_s; t2[threadIdx.x] = 0.f;
    volatile float* t3 = y2s;    t3[threadIdx.x & 255] = 0.f;
    volatile float* t4 = smax;   if (threadIdx.x < 4) t4[threadIdx.x] = 0.f; }

  y2s[threadIdx.x] = y2[ck * 256 + threadIdx.x];

  bf16x8 a0[4], a1[4];
  #pragma unroll
  for (int kk = 0; kk < 4; ++kk) {
    a0[kk] = *(const bf16x8*)(xf + (size_t)(bi * 8 + wv * 2) * 2048 + kk * 512 + lane * 8);
    a1[kk] = *(const bf16x8*)(xf + (size_t)(bi * 8 + wv * 2 + 1) * 2048 + kk * 512 + lane * 8);
    if (MODE == 0) { sink_bf(a0[kk]); sink_bf(a1[kk]); }
  }
  f4 xi0 = *(const f4*)(x2 + r0 + fg * 4);
  f4 xi1 = *(const f4*)(x2 + r0 + 16 + fg * 4);

  #define STAGE2(buf, pj) do { \
    const unsigned short* _g = yf + (size_t)(ck * 16 + (pj) * 2) * 2048; \
    _Pragma("unroll") \
    for (int q = 0; q < 2; ++q) { \
      int s_ = q * 4 + wv; \
      GLOAD_LDS16(_g + s_ * 512 + lane * 8, &bld[buf][s_ * 512]); \
    } \
  } while (0)

  float rs0[4] = {0.f,0.f,0.f,0.f};
  float rs1[4] = {0.f,0.f,0.f,0.f};
  float dm = 0.f;
  int cq = (wv * 4 + fg) * 256;

  for (int rep = 0; rep < REP; ++rep) {
    int cur = 0;
    STAGE2(0, 0);
    __syncthreads();
    for (int j = 0; j < 8; ++j) {
      if (j < 7) {
        STAGE2(cur ^ 1, j + 1);
        asm volatile("s_waitcnt vmcnt(2)" ::: "memory");
      } else {
        asm volatile("s_waitcnt vmcnt(0)" ::: "memory");
      }
      __builtin_amdgcn_s_barrier();

      if (MODE >= 1) {
        #pragma unroll
        for (int n = 0; n < 2; ++n) {
          f32x4 acc0 = (f32x4){0.f,0.f,0.f,0.f};
          f32x4 acc1 = (f32x4){0.f,0.f,0.f,0.f};
          #pragma unroll
          for (int kk = 0; kk < 4; ++kk) {
            bf16x8 b = *(const bf16x8*)(&bld[cur][n * 2048 + kk * 512 + lane * 8]);
            acc0 = __builtin_amdgcn_mfma_f32_16x16x32_bf16(a0[kk], b, acc0, 0, 0, 0);
            acc1 = __builtin_amdgcn_mfma_f32_16x16x32_bf16(a1[kk], b, acc1, 0, 0, 0);
          }
          if (MODE == 1) { sink_f4(acc0); sink_f4(acc1); }
          if (MODE == 2) {
            float y2n = y2s[j * 32 + n * 16 + fr];
            float cs = 0.f;
            #pragma unroll
            for (int r = 0; r < 4; ++r) {
              float d20 = xi0[r] + y2n - 2.0f * acc0[r];
              float d21 = xi1[r] + y2n - 2.0f * acc1[r];
              dm = fmaxf(dm, fmaxf(d20, d21));
              float w0 = __builtin_amdgcn_sqrtf(fmaxf(d20, 0.f));
              float w1 = __builtin_amdgcn_sqrtf(fmaxf(d21, 0.f));
              rs0[r] += w0; rs1[r] += w1;
              cs += w0 + w1;
            }
            csum_s[cq + j * 32 + n * 16 + fr] = cs;
          }
        }
      }
      __builtin_amdgcn_s_barrier();
      cur ^= 1;
    }
  }
  // token (keeps MODE2 epilogue live; harmless scratch write)
  float tok = rs0[0] + rs1[0] + dm + xi0[0] + xi1[0];
  if (threadIdx.x == 0) diag[bid] = tok;
  #undef STAGE2
}

// ---- single merged reduction: 3MB in, 128KB out; fixed-order fp64 ----
__global__ __launch_bounds__(256) void reduce_rc(const float* __restrict__ Rpart,
    const float* __restrict__ Cpart, double* __restrict__ Rd, double* __restrict__ Cd) {
  int t = blockIdx.x * blockDim.x + threadIdx.x;  // 16384 threads
  if (t < Nn) {
    double s0 = 0.0, s1 = 0.0, s2 = 0.0, s3 = 0.0;
    double s4 = 0.0, s5 = 0.0, s6 = 0.0, s7 = 0.0;
    #pragma unroll
    for (int i = 0; i < 4; ++i) {
      s0 += (double)Rpart[(size_t)(i * 8 + 0) * Nn + t];
      s1 += (double)Rpart[(size_t)(i * 8 + 1) * Nn + t];
      s2 += (double)Rpart[(size_t)(i * 8 + 2) * Nn + t];
      s3 += (double)Rpart[(size_t)(i * 8 + 3) * Nn + t];
      s4 += (double)Rpart[(size_t)(i * 8 + 4) * Nn + t];
      s5 += (double)Rpart[(size_t)(i * 8 + 5) * Nn + t];
      s6 += (double)Rpart[(size_t)(i * 8 + 6) * Nn + t];
      s7 += (double)Rpart[(size_t)(i * 8 + 7) * Nn + t];
    }
    Rd[t] = ((s0 + s1) + (s2 + s3)) + ((s4 + s5) + (s6 + s7));
  } else {
    int c = t - Nn;
    double s0 = 0.0, s1 = 0.0, s2 = 0.0, s3 = 0.0;
    double s4 = 0.0, s5 = 0.0, s6 = 0.0, s7 = 0.0;
    #pragma unroll
    for (int i = 0; i < 8; ++i) {
      s0 += (double)Cpart[(size_t)(i * 8 + 0) * Mm + c];
      s1 += (double)Cpart[(size_t)(i * 8 + 1) * Mm + c];
      s2 += (double)Cpart[(size_t)(i * 8 + 2) * Mm + c];
      s3 += (double)Cpart[(size_t)(i * 8 + 3) * Mm + c];
      s4 += (double)Cpart[(size_t)(i * 8 + 4) * Mm + c];
      s5 += (double)Cpart[(size_t)(i * 8 + 5) * Mm + c];
      s6 += (double)Cpart[(size_t)(i * 8 + 6) * Mm + c];
      s7 += (double)Cpart[(size_t)(i * 8 + 7) * Mm + c];
    }
    Cd[c] = ((s0 + s1) + (s2 + s3)) + ((s4 + s5) + (s6 + s7));
  }
}

__device__ __forceinline__ double bred(double v, double* sb) {
  int tid = threadIdx.x;
  #pragma unroll
  for (int m = 1; m < 64; m <<= 1) v += __shfl_xor(v, m, 64);
  __syncthreads();
  if ((tid & 63) == 0) sb[tid >> 6] = v;
  __syncthreads();
  double s = (tid < 16) ? sb[tid] : 0.0;
  if (tid < 64) {
    #pragma unroll
    for (int m = 1; m < 16; m <<= 1) s += __shfl_xor(s, m, 16);
  }
  if (tid == 0) sb[0] = s;
  __syncthreads();
  return sb[0];
}

// ---- closed-form Sinkhorn from (R, C, Wmax) ----
__global__ __launch_bounds__(1024) void solve(const double* __restrict__ Rd,
    const double* __restrict__ Cd, const float* __restrict__ wmaxp,
    float* __restrict__ out) {
  __shared__ double sb[16];
  __shared__ float smx[16];
  int tid = threadIdx.x;
  float wl = fmaxf(wmaxp[tid], wmaxp[tid + 1024]);  // 2048 partials
  #pragma unroll
  for (int m = 1; m < 64; m <<= 1) wl = fmaxf(wl, __shfl_xor(wl, m, 64));
  if ((tid & 63) == 0) smx[tid >> 6] = wl;
  __syncthreads();
  float wg = (tid < 16) ? smx[tid] : 0.f;
  if (tid < 64) {
    #pragma unroll
    for (int m = 1; m < 16; m <<= 1) wg = fmaxf(wg, __shfl_xor(wg, m, 16));
  }
  if (tid == 0) smx[0] = wg;
  __syncthreads();
  double wmax = (double)smx[0];
  double c = EPS / (128.0 * wmax);
  const double invm = 1.0 / 8192.0;
  double R[8], C[8];
  #pragma unroll
  for (int k = 0; k < 8; ++k) { R[k] = Rd[tid * 8 + k]; C[k] = Cd[tid * 8 + k]; }

  double part = 0.0;
  #pragma unroll
  for (int k = 0; k < 8; ++k) part += 1.0 / (1.0 - c * invm * R[k]);
  double S_u1 = bred(part, sb);
  double cu1 = c * (S_u1 * invm);
  part = 0.0;
  #pragma unroll
  for (int k = 0; k < 8; ++k) part += 1.0 / (S_u1 - cu1 * C[k]);
  double S_v1 = bred(part, sb);
  double cv1 = c * (S_v1 * invm);
  double u2[8];
  part = 0.0;
  #pragma unroll
  for (int k = 0; k < 8; ++k) { u2[k] = 1.0 / (S_v1 - cv1 * R[k]); part += u2[k]; }
  double S_u2 = bred(part, sb);
  double cu2 = c * (S_u2 * invm);
  part = 0.0;
  #pragma unroll
  for (int k = 0; k < 8; ++k) part += 1.0 / (S_u2 - cu2 * C[k]);
  double S_v2 = bred(part, sb);
  double cv2 = c * (S_v2 * invm);
  part = 0.0;
  #pragma unroll
  for (int k = 0; k < 8; ++k) part += u2[k] * (S_v2 - cv2 * R[k]);
  double div = bred(part, sb);
  if (tid == 0) out[0] = (float)(div * invm);  // reduction='mean'
}

extern "C" void kernel_launch(void* const* d_in, const int* in_sizes, int n_in,
                              void* d_out, int out_size, void* d_ws, size_t ws_size,
                              hipStream_t stream) {
  const float* x = (const float*)d_in[0];
  const float* y = (const float*)d_in[1];
  char* ws = (char*)d_ws;
  size_t off = 0;
  unsigned short* xf = (unsigned short*)(ws + off); off += (size_t)Nn * DIM * 2;
  unsigned short* yf = (unsigned short*)(ws + off); off += (size_t)Mm * DIM * 2;
  float* x2 = (float*)(ws + off); off += (size_t)Nn * 4;
  float* y2 = (float*)(ws + off); off += (size_t)Mm * 4;
  float* Rpart = (float*)(ws + off); off += (size_t)RBAND * Nn * 4;    // 1 MiB
  float* Cpart = (float*)(ws + off); off += (size_t)CBAND * Mm * 4;    // 2 MiB
  double* Rd = (double*)(ws + off); off += (size_t)Nn * 8;
  double* Cd = (double*)(ws + off); off += (size_t)Mm * 8;
  float* wmaxp = (float*)(ws + off); off += 2048 * 4;
  float* diag = (float*)(ws + off); off += 2048 * 4;

  prep_all<<<1024, 256, 0, stream>>>(x, y, xf, yf, x2, y2);
  fused_sweep<<<2048, 256, 0, stream>>>(xf, yf, x2, y2, Rpart, Cpart, wmaxp);
  reduce_rc<<<64, 256, 0, stream>>>(Rpart, Cpart, Rd, Cd);
  solve<<<1, 1024, 0, stream>>>(Rd, Cd, wmaxp, (float*)d_out);

  // R14 diagnostics (removed next round): amplified phase ablation of fused_sweep
  fused_diag<0, 8><<<2048, 256, 0, stream>>>(xf, yf, x2, y2, diag);
  fused_diag<1, 4><<<2048, 256, 0, stream>>>(xf, yf, x2, y2, diag);
  fused_diag<2, 2><<<2048, 256, 0, stream>>>(xf, yf, x2, y2, diag);
}

// Round 15
// 56.934 us; speedup vs baseline: 3.3639x; 3.3639x over previous
//
#include <hip/hip_runtime.h>
#include <hip/hip_bf16.h>
#include <math.h>

#define Nn 8192
#define Mm 8192
#define DIM 128
#define EPS 0.001
#define RBAND 32     // 32 ck col-chunks -> fully fr-reduced row bands
#define CBAND 64     // 64 bi row-blocks -> fully (wv,fg)-reduced col bands

typedef __attribute__((ext_vector_type(8))) short bf16x8;
typedef __attribute__((ext_vector_type(4))) float f32x4;
typedef __attribute__((ext_vector_type(4))) float f4;
typedef __attribute__((ext_vector_type(4))) unsigned int u32x4;

__device__ __forceinline__ unsigned int pack2bf(float a, float b) {
  __hip_bfloat16 ha = __float2bfloat16(a), hb = __float2bfloat16(b);
  return (unsigned int)*(unsigned short*)&ha | ((unsigned int)*(unsigned short*)&hb << 16);
}

// ---- prep: FRAGMENT-MAJOR bf16 for both X and Y + squared norms (proven R5-R14). ----
__global__ __launch_bounds__(256) void prep_all(const float* __restrict__ X,
    const float* __restrict__ Y, unsigned short* __restrict__ Xf,
    unsigned short* __restrict__ Yf, float* __restrict__ X2, float* __restrict__ Y2) {
  int bid = blockIdx.x;                               // 1024 blocks: 512 X + 512 Y
  const float* src = (bid < 512) ? X : Y;
  unsigned short* dst = (bid < 512) ? Xf : Yf;
  float* dn = (bid < 512) ? X2 : Y2;
  int gid = (bid & 511) * 256 + threadIdx.x;          // 131072 = 8192 rows x 16 g
  int row = gid >> 4, g = gid & 15;
  f4 p0 = *(const f4*)(src + (size_t)row * DIM + g * 8);
  f4 p1 = *(const f4*)(src + (size_t)row * DIM + g * 8 + 4);
  u32x4 packed;
  packed[0] = pack2bf(p0[0], p0[1]);
  packed[1] = pack2bf(p0[2], p0[3]);
  packed[2] = pack2bf(p1[0], p1[1]);
  packed[3] = pack2bf(p1[2], p1[3]);
  int kk = g >> 2, fg = g & 3, t = row >> 4, fr = row & 15;
  *(u32x4*)(dst + (size_t)t * 2048 + kk * 512 + (fg * 16 + fr) * 8) = packed;
  float s = p0[0]*p0[0] + p0[1]*p0[1] + p0[2]*p0[2] + p0[3]*p0[3]
          + p1[0]*p1[0] + p1[1]*p1[1] + p1[2]*p1[2] + p1[3]*p1[3];
  s += __shfl_xor(s, 1, 64); s += __shfl_xor(s, 2, 64);
  s += __shfl_xor(s, 4, 64); s += __shfl_xor(s, 8, 64);
  if (g == 0) dn[row] = s;
}

// issue one 1KB wave-DMA: global (per-lane addr) -> LDS (wave-uniform base + lane*16)
#define GLOAD_LDS16(gsrc, ldst) \
  __builtin_amdgcn_global_load_lds( \
      (const __attribute__((address_space(1))) unsigned int*)(gsrc), \
      (__attribute__((address_space(3))) unsigned int*)(ldst), 16, 0, 0)

// ---- fused stripe-sweep v6: TRIPLE-buffered B staging, ONE barrier per j-step.
// (R14 diag: skeleton ~1/4, ds_read+MFMA ~1/4, epilogue ~1/2 of the ~31us loop;
// this round halves the skeleton's barrier count: vmcnt(2) retires stage(j), one
// barrier publishes it AND protects buf (j+2)%3 == (j-1)%3; STAGE issues after.) ----
__global__ __launch_bounds__(256) void fused_sweep(const unsigned short* __restrict__ xf,
    const unsigned short* __restrict__ yf, const float* __restrict__ x2,
    const float* __restrict__ y2, float* __restrict__ Rpart, float* __restrict__ Cpart,
    float* __restrict__ wmaxp) {
  int bid = blockIdx.x;            // 2048 = 64 row-blocks x 32 chunks
  int bi = bid >> 5;               // row-block 0..63 (128 rows)
  int ck = bid & 31;               // col-chunk 0..31 (256 cols)
  int wv = threadIdx.x >> 6, lane = threadIdx.x & 63;
  int fr = lane & 15, fg = lane >> 4;
  int r0 = bi * 128 + wv * 32;

  __shared__ __attribute__((aligned(16))) unsigned short bld[3][4096]; // 3 x 8KB panels
  __shared__ float csum_s[16 * 256];   // 16KB
  __shared__ float rsum_s[4 * 512];    // 8KB
  __shared__ float y2s[256];
  __shared__ float smax[4];

  y2s[threadIdx.x] = y2[ck * 256 + threadIdx.x];

  bf16x8 a0[4], a1[4];
  #pragma unroll
  for (int kk = 0; kk < 4; ++kk) {
    a0[kk] = *(const bf16x8*)(xf + (size_t)(bi * 8 + wv * 2) * 2048 + kk * 512 + lane * 8);
    a1[kk] = *(const bf16x8*)(xf + (size_t)(bi * 8 + wv * 2 + 1) * 2048 + kk * 512 + lane * 8);
  }
  f4 xi0 = *(const f4*)(x2 + r0 + fg * 4);
  f4 xi1 = *(const f4*)(x2 + r0 + 16 + fg * 4);

  #define STAGE(buf, pj) do { \
    const unsigned short* _g = yf + (size_t)(ck * 16 + (pj) * 2) * 2048; \
    _Pragma("unroll") \
    for (int q = 0; q < 2; ++q) { \
      int s_ = q * 4 + wv; \
      GLOAD_LDS16(_g + s_ * 512 + lane * 8, &bld[buf][s_ * 512]); \
    } \
  } while (0)

  // prologue: prefetch panels 0 and 1 (buffers 0,1); syncthreads covers y2s too
  STAGE(0, 0);
  STAGE(1, 1);
  __syncthreads();

  float rs0[4] = {0.f,0.f,0.f,0.f};
  float rs1[4] = {0.f,0.f,0.f,0.f};
  float dm = 0.f;
  int cq = (wv * 4 + fg) * 256;

  for (int j = 0; j < 8; ++j) {
    // retire stage(j): outstanding FIFO is [stage(j):2][stage(j+1):2] (if issued)
    if (j < 7) {
      asm volatile("s_waitcnt vmcnt(2)" ::: "memory");
    } else {
      asm volatile("s_waitcnt vmcnt(0)" ::: "memory");
    }
    // ONE barrier: publishes stage(j) (each wave passed its own vmcnt) AND ensures
    // all waves finished reading buf (j+2)%3 == (j-1)%3 in iteration j-1.
    __builtin_amdgcn_s_barrier();
    if (j < 6) STAGE((j + 2) % 3, j + 2);

    int cur = j % 3;
    #pragma unroll
    for (int n = 0; n < 2; ++n) {
      float y2n = y2s[j * 32 + n * 16 + fr];
      f32x4 acc0 = (f32x4){0.f,0.f,0.f,0.f};
      f32x4 acc1 = (f32x4){0.f,0.f,0.f,0.f};
      #pragma unroll
      for (int kk = 0; kk < 4; ++kk) {
        bf16x8 b = *(const bf16x8*)(&bld[cur][n * 2048 + kk * 512 + lane * 8]);
        acc0 = __builtin_amdgcn_mfma_f32_16x16x32_bf16(a0[kk], b, acc0, 0, 0, 0);
        acc1 = __builtin_amdgcn_mfma_f32_16x16x32_bf16(a1[kk], b, acc1, 0, 0, 0);
      }
      float cs = 0.f;
      #pragma unroll
      for (int r = 0; r < 4; ++r) {
        float d20 = xi0[r] + y2n - 2.0f * acc0[r];
        float d21 = xi1[r] + y2n - 2.0f * acc1[r];
        dm = fmaxf(dm, fmaxf(d20, d21));           // clang fuses to v_max3_f32
        float w0 = __builtin_amdgcn_sqrtf(fmaxf(d20, 0.f));
        float w1 = __builtin_amdgcn_sqrtf(fmaxf(d21, 0.f));
        rs0[r] += w0; rs1[r] += w1;
        cs += w0 + w1;
      }
      csum_s[cq + j * 32 + n * 16 + fr] = cs;      // lane-exclusive slot, read after tail sync
    }
  }

  #pragma unroll
  for (int r = 0; r < 4; ++r) {
    rsum_s[wv * 512 + fr * 32 + fg * 4 + r] = rs0[r];
    rsum_s[wv * 512 + fr * 32 + 16 + fg * 4 + r] = rs1[r];
  }
  float wm = __builtin_amdgcn_sqrtf(fmaxf(dm, 0.f));
  #pragma unroll
  for (int mask = 1; mask < 64; mask <<= 1) wm = fmaxf(wm, __shfl_xor(wm, mask, 64));
  if (lane == 0) smax[wv] = wm;
  __syncthreads();

  // tail: fully-reduced partial emission (fixed order)
  {
    int tid = threadIdx.x;
    float s = 0.f;
    #pragma unroll
    for (int q = 0; q < 16; ++q) s += csum_s[q * 256 + tid];
    Cpart[(size_t)bi * Mm + ck * 256 + tid] = s;
    if (tid < 128) {
      int w = tid >> 5, lr = tid & 31;
      float t2 = 0.f;
      #pragma unroll
      for (int f = 0; f < 16; ++f) t2 += rsum_s[w * 512 + f * 32 + lr];
      Rpart[(size_t)ck * Nn + bi * 128 + tid] = t2;
    }
    if (tid == 0)
      wmaxp[bid] = fmaxf(fmaxf(smax[0], smax[1]), fmaxf(smax[2], smax[3]));
  }
  #undef STAGE
}

// ---- single merged reduction: 3MB in, 128KB out; fixed-order fp64 ----
__global__ __launch_bounds__(256) void reduce_rc(const float* __restrict__ Rpart,
    const float* __restrict__ Cpart, double* __restrict__ Rd, double* __restrict__ Cd) {
  int t = blockIdx.x * blockDim.x + threadIdx.x;  // 16384 threads
  if (t < Nn) {
    double s0 = 0.0, s1 = 0.0, s2 = 0.0, s3 = 0.0;
    double s4 = 0.0, s5 = 0.0, s6 = 0.0, s7 = 0.0;
    #pragma unroll
    for (int i = 0; i < 4; ++i) {
      s0 += (double)Rpart[(size_t)(i * 8 + 0) * Nn + t];
      s1 += (double)Rpart[(size_t)(i * 8 + 1) * Nn + t];
      s2 += (double)Rpart[(size_t)(i * 8 + 2) * Nn + t];
      s3 += (double)Rpart[(size_t)(i * 8 + 3) * Nn + t];
      s4 += (double)Rpart[(size_t)(i * 8 + 4) * Nn + t];
      s5 += (double)Rpart[(size_t)(i * 8 + 5) * Nn + t];
      s6 += (double)Rpart[(size_t)(i * 8 + 6) * Nn + t];
      s7 += (double)Rpart[(size_t)(i * 8 + 7) * Nn + t];
    }
    Rd[t] = ((s0 + s1) + (s2 + s3)) + ((s4 + s5) + (s6 + s7));
  } else {
    int c = t - Nn;
    double s0 = 0.0, s1 = 0.0, s2 = 0.0, s3 = 0.0;
    double s4 = 0.0, s5 = 0.0, s6 = 0.0, s7 = 0.0;
    #pragma unroll
    for (int i = 0; i < 8; ++i) {
      s0 += (double)Cpart[(size_t)(i * 8 + 0) * Mm + c];
      s1 += (double)Cpart[(size_t)(i * 8 + 1) * Mm + c];
      s2 += (double)Cpart[(size_t)(i * 8 + 2) * Mm + c];
      s3 += (double)Cpart[(size_t)(i * 8 + 3) * Mm + c];
      s4 += (double)Cpart[(size_t)(i * 8 + 4) * Mm + c];
      s5 += (double)Cpart[(size_t)(i * 8 + 5) * Mm + c];
      s6 += (double)Cpart[(size_t)(i * 8 + 6) * Mm + c];
      s7 += (double)Cpart[(size_t)(i * 8 + 7) * Mm + c];
    }
    Cd[c] = ((s0 + s1) + (s2 + s3)) + ((s4 + s5) + (s6 + s7));
  }
}

__device__ __forceinline__ double bred(double v, double* sb) {
  int tid = threadIdx.x;
  #pragma unroll
  for (int m = 1; m < 64; m <<= 1) v += __shfl_xor(v, m, 64);
  __syncthreads();
  if ((tid & 63) == 0) sb[tid >> 6] = v;
  __syncthreads();
  double s = (tid < 16) ? sb[tid] : 0.0;
  if (tid < 64) {
    #pragma unroll
    for (int m = 1; m < 16; m <<= 1) s += __shfl_xor(s, m, 16);
  }
  if (tid == 0) sb[0] = s;
  __syncthreads();
  return sb[0];
}

// ---- closed-form Sinkhorn from (R, C, Wmax); exact to fp32 resolution since
// K = 1 - cW with cW <= 7.8e-6. Convergence fires at it=1 (ref freeze). ----
__global__ __launch_bounds__(1024) void solve(const double* __restrict__ Rd,
    const double* __restrict__ Cd, const float* __restrict__ wmaxp,
    float* __restrict__ out) {
  __shared__ double sb[16];
  __shared__ float smx[16];
  int tid = threadIdx.x;
  float wl = fmaxf(wmaxp[tid], wmaxp[tid + 1024]);  // 2048 partials
  #pragma unroll
  for (int m = 1; m < 64; m <<= 1) wl = fmaxf(wl, __shfl_xor(wl, m, 64));
  if ((tid & 63) == 0) smx[tid >> 6] = wl;
  __syncthreads();
  float wg = (tid < 16) ? smx[tid] : 0.f;
  if (tid < 64) {
    #pragma unroll
    for (int m = 1; m < 16; m <<= 1) wg = fmaxf(wg, __shfl_xor(wg, m, 16));
  }
  if (tid == 0) smx[0] = wg;
  __syncthreads();
  double wmax = (double)smx[0];
  double c = EPS / (128.0 * wmax);
  const double invm = 1.0 / 8192.0;
  double R[8], C[8];
  #pragma unroll
  for (int k = 0; k < 8; ++k) { R[k] = Rd[tid * 8 + k]; C[k] = Cd[tid * 8 + k]; }

  double part = 0.0;
  #pragma unroll
  for (int k = 0; k < 8; ++k) part += 1.0 / (1.0 - c * invm * R[k]);
  double S_u1 = bred(part, sb);
  double cu1 = c * (S_u1 * invm);
  part = 0.0;
  #pragma unroll
  for (int k = 0; k < 8; ++k) part += 1.0 / (S_u1 - cu1 * C[k]);
  double S_v1 = bred(part, sb);
  double cv1 = c * (S_v1 * invm);
  double u2[8];
  part = 0.0;
  #pragma unroll
  for (int k = 0; k < 8; ++k) { u2[k] = 1.0 / (S_v1 - cv1 * R[k]); part += u2[k]; }
  double S_u2 = bred(part, sb);
  double cu2 = c * (S_u2 * invm);
  part = 0.0;
  #pragma unroll
  for (int k = 0; k < 8; ++k) part += 1.0 / (S_u2 - cu2 * C[k]);
  double S_v2 = bred(part, sb);
  double cv2 = c * (S_v2 * invm);
  part = 0.0;
  #pragma unroll
  for (int k = 0; k < 8; ++k) part += u2[k] * (S_v2 - cv2 * R[k]);
  double div = bred(part, sb);
  if (tid == 0) out[0] = (float)(div * invm);  // reduction='mean'
}

extern "C" void kernel_launch(void* const* d_in, const int* in_sizes, int n_in,
                              void* d_out, int out_size, void* d_ws, size_t ws_size,
                              hipStream_t stream) {
  const float* x = (const float*)d_in[0];
  const float* y = (const float*)d_in[1];
  char* ws = (char*)d_ws;
  size_t off = 0;
  unsigned short* xf = (unsigned short*)(ws + off); off += (size_t)Nn * DIM * 2;
  unsigned short* yf = (unsigned short*)(ws + off); off += (size_t)Mm * DIM * 2;
  float* x2 = (float*)(ws + off); off += (size_t)Nn * 4;
  float* y2 = (float*)(ws + off); off += (size_t)Mm * 4;
  float* Rpart = (float*)(ws + off); off += (size_t)RBAND * Nn * 4;    // 1 MiB
  float* Cpart = (float*)(ws + off); off += (size_t)CBAND * Mm * 4;    // 2 MiB
  double* Rd = (double*)(ws + off); off += (size_t)Nn * 8;
  double* Cd = (double*)(ws + off); off += (size_t)Mm * 8;
  float* wmaxp = (float*)(ws + off); off += 2048 * 4;

  prep_all<<<1024, 256, 0, stream>>>(x, y, xf, yf, x2, y2);
  fused_sweep<<<2048, 256, 0, stream>>>(xf, yf, x2, y2, Rpart, Cpart, wmaxp);
  reduce_rc<<<64, 256, 0, stream>>>(Rpart, Cpart, Rd, Cd);
  solve<<<1, 1024, 0, stream>>>(Rd, Cd, wmaxp, (float*)d_out);
}